// Round 2
// baseline (62.381 us; speedup 1.0000x reference)
//
#include <hip/hip_runtime.h>

typedef __attribute__((ext_vector_type(8))) short short8;
typedef __attribute__((ext_vector_type(4))) float f32x4;

#define B_TOTAL 20000
#define BT      32          // b-rows per block; 20000 = 625*32 exactly
#define NBLK    625
#define NF      256
#define K2      512
#define NS      10

__device__ __forceinline__ unsigned short f2bf(float x) {
    unsigned u = __builtin_bit_cast(unsigned, x);
    u += 0x7FFFu + ((u >> 16) & 1u);   // round-to-nearest-even
    return (unsigned short)(u >> 16);
}

// K1: W [256][512] f32 -> bf16 in ws
__global__ __launch_bounds__(256) void wconvert(const float* __restrict__ w,
                                                unsigned short* __restrict__ wbf) {
    const int i = (blockIdx.x * 256 + threadIdx.x) * 4;
    const float4 v = *(const float4*)(w + i);
    ushort4 o;
    o.x = f2bf(v.x); o.y = f2bf(v.y); o.z = f2bf(v.z); o.w = f2bf(v.w);
    *(ushort4*)(wbf + i) = o;
}

// K2: fused gather + GEMM + relu. Block = 32 b-rows x 256 e-rows.
// LDS comb: swizzled [kc 64][row 32][8 bf16] = 32 KB; byte ^= (kc&7)<<4.
__global__ __launch_bounds__(256) void fused(
    const float* __restrict__ ue, const int* __restrict__ nidx,
    const int* __restrict__ nodes, const unsigned short* __restrict__ wbf,
    float* __restrict__ out)
{
    __shared__ unsigned short comb[64 * BT * 8];   // 32 KB
    const int t    = threadIdx.x;
    const int lane = t & 63;
    const int wv   = t >> 6;
    const int n0   = blockIdx.x * BT;

    // ---- Phase 1: gather 8 rows per wave ----
    {
        const int r0 = wv * 8;
        const int b0 = n0 + r0;
        // bulk-prefetch indices: 80 contiguous nidx ints + 8 nodes per wave
        const int idxA = nidx[b0 * NS + lane];                       // positions 0..63
        const int idxB = (lane < 16) ? nidx[b0 * NS + 64 + lane] : 0; // positions 64..79
        const int nodv = (lane < 8) ? nodes[b0 + lane] : 0;

        const int kcS   = lane >> 1;              // self k-chunk
        const int swz   = (kcS & 7) << 4;         // same for neigh (32+kcS ≡ kcS mod 8)
        const int half8 = (lane & 1) * 8;

        #pragma unroll
        for (int r = 0; r < 8; ++r) {
            const int row = r0 + r;
            const int nd  = __shfl(nodv, r);
            const float4 sf = ((const float4*)(ue + (size_t)nd * NF))[lane];
            float ax = 0.f, ay = 0.f, az = 0.f, aw = 0.f;
            #pragma unroll
            for (int s = 0; s < NS; ++s) {
                const int p  = r * NS + s;
                const int is = (p < 64) ? __shfl(idxA, p) : __shfl(idxB, p - 64);
                const float4 v = ((const float4*)(ue + (size_t)is * NF))[lane];
                ax += v.x; ay += v.y; az += v.z; aw += v.w;
            }
            const float inv = 1.0f / 11.0f;       // reference divides by S+1
            ushort4 s4, n4;
            s4.x = f2bf(sf.x); s4.y = f2bf(sf.y); s4.z = f2bf(sf.z); s4.w = f2bf(sf.w);
            n4.x = f2bf(ax * inv); n4.y = f2bf(ay * inv);
            n4.z = f2bf(az * inv); n4.w = f2bf(aw * inv);
            const int byteS = (((kcS       ) * BT + row) * 16 + half8) ^ swz;
            const int byteN = (((kcS + 32  ) * BT + row) * 16 + half8) ^ swz;
            *(ushort4*)((char*)comb + byteS) = s4;
            *(ushort4*)((char*)comb + byteN) = n4;
        }
    }
    __syncthreads();

    // ---- Phase 2: GEMM, no barriers. Wave wv owns e-rows [wv*64, wv*64+64). ----
    const int fr = lane & 15;
    const int kq = lane >> 4;
    const unsigned short* wp = wbf + (size_t)(wv * 64 + fr) * K2 + kq * 8;

    f32x4 acc[4][2] = {};
    #pragma unroll
    for (int ks = 0; ks < 16; ++ks) {
        short8 af[4];
        #pragma unroll
        for (int i = 0; i < 4; ++i)
            af[i] = *(const short8*)(wp + (size_t)i * 16 * K2 + ks * 32);
        short8 bg[2];
        const int kc = ks * 4 + kq;
        #pragma unroll
        for (int j = 0; j < 2; ++j) {
            const int byte = ((kc * BT + j * 16 + fr) * 16) ^ ((kc & 7) << 4);
            bg[j] = *(const short8*)((const char*)comb + byte);
        }
        #pragma unroll
        for (int i = 0; i < 4; ++i)
            #pragma unroll
            for (int j = 0; j < 2; ++j)
                acc[i][j] = __builtin_amdgcn_mfma_f32_16x16x32_bf16(af[i], bg[j], acc[i][j], 0, 0, 0);
    }

    // ---- Epilogue: relu + store ----
    #pragma unroll
    for (int i = 0; i < 4; ++i) {
        const int e = wv * 64 + i * 16 + kq * 4;
        #pragma unroll
        for (int j = 0; j < 2; ++j) {
            const int b = n0 + j * 16 + fr;
            #pragma unroll
            for (int r = 0; r < 4; ++r)
                out[(size_t)(e + r) * B_TOTAL + b] = fmaxf(acc[i][j][r], 0.0f);
        }
    }
}

extern "C" void kernel_launch(void* const* d_in, const int* in_sizes, int n_in,
                              void* d_out, int out_size, void* d_ws, size_t ws_size,
                              hipStream_t stream) {
    const float* ue    = (const float*)d_in[0];
    // d_in[1] = features_ap: unused (ue2ue mode)
    const int*   nidx  = (const int*)d_in[2];
    const int*   nodes = (const int*)d_in[3];
    const float* w     = (const float*)d_in[4];
    float*       out   = (float*)d_out;

    unsigned short* wbf = (unsigned short*)d_ws;   // [256][512] bf16 = 256 KB

    hipLaunchKernelGGL(wconvert, dim3(128), dim3(256), 0, stream, w, wbf);
    hipLaunchKernelGGL(fused, dim3(NBLK), dim3(256), 0, stream,
                       ue, nidx, nodes, wbf, out);
}